// Round 3
// baseline (235.155 us; speedup 1.0000x reference)
//
#include <hip/hip_runtime.h>
#include <math.h>

#define NN 256
#define TT 256
#define DD 1024
#define HH 1024

// ---------------------------------------------------------------------------
// Kernel 1a: max-pool partials, contiguous-window grid-stride form.
// grid (2048, 2) x 256. Thread g (0..2^19-1): d4 = g&255 (float4 col),
// tt = (g>>8)&7, n = g>>11. Reads rows t = tt + 8k, k=0..31: address
// base + k*2048 (f4). At each k the whole grid reads 256 contiguous 32KB
// windows (one per n) sweeping 512MB linearly -> DRAM-friendly frontier.
// 8 loads in flight per thread, 8 independent max accumulators.
// ---------------------------------------------------------------------------
__global__ __launch_bounds__(256) void pool_partial(const float* __restrict__ subs,
                                                    const float* __restrict__ objs,
                                                    float* __restrict__ partial) {
    const int which = blockIdx.y;
    const float4* src = reinterpret_cast<const float4*>(which == 0 ? subs : objs);
    const unsigned g = blockIdx.x * 256u + threadIdx.x;  // 0..524287
    const unsigned d4 = g & 255u;
    const unsigned tt = (g >> 8) & 7u;
    const unsigned n  = g >> 11;
    const float4* base = src + (((size_t)n << 16) + (tt << 8) + d4);

    float4 a[8];
#pragma unroll
    for (int s = 0; s < 8; ++s) a[s] = make_float4(-INFINITY, -INFINITY, -INFINITY, -INFINITY);

    for (int k = 0; k < 32; k += 8) {
        float4 v[8];
#pragma unroll
        for (int s = 0; s < 8; ++s) v[s] = base[(size_t)(k + s) * 2048];
#pragma unroll
        for (int s = 0; s < 8; ++s) {
            a[s].x = fmaxf(a[s].x, v[s].x);
            a[s].y = fmaxf(a[s].y, v[s].y);
            a[s].z = fmaxf(a[s].z, v[s].z);
            a[s].w = fmaxf(a[s].w, v[s].w);
        }
    }
#pragma unroll
    for (int s = 0; s < 4; ++s) {
        a[s].x = fmaxf(a[s].x, a[s + 4].x); a[s].y = fmaxf(a[s].y, a[s + 4].y);
        a[s].z = fmaxf(a[s].z, a[s + 4].z); a[s].w = fmaxf(a[s].w, a[s + 4].w);
    }
    float4 m;
    m.x = fmaxf(fmaxf(a[0].x, a[1].x), fmaxf(a[2].x, a[3].x));
    m.y = fmaxf(fmaxf(a[0].y, a[1].y), fmaxf(a[2].y, a[3].y));
    m.z = fmaxf(fmaxf(a[0].z, a[1].z), fmaxf(a[2].z, a[3].z));
    m.w = fmaxf(fmaxf(a[0].w, a[1].w), fmaxf(a[2].w, a[3].w));
    // partial[(which*8 + tt)][n][d4]  (float4 units)
    reinterpret_cast<float4*>(partial)[(((size_t)(which * 8 + tt) * NN) + n) * 256 + d4] = m;
}

// Kernel 1b: reduce 8 tt-partials. grid (256, 2), block 256.
__global__ __launch_bounds__(256) void pool_reduce(const float* __restrict__ partial,
                                                   float* __restrict__ pooled) {
    const int n = blockIdx.x;
    const int which = blockIdx.y;
    const int d4 = threadIdx.x;
    const float4* p = reinterpret_cast<const float4*>(partial);
    float4 m = make_float4(-INFINITY, -INFINITY, -INFINITY, -INFINITY);
#pragma unroll
    for (int tt = 0; tt < 8; ++tt) {
        float4 v = p[(((size_t)(which * 8 + tt) * NN) + n) * 256 + d4];
        m.x = fmaxf(m.x, v.x); m.y = fmaxf(m.y, v.y);
        m.z = fmaxf(m.z, v.z); m.w = fmaxf(m.w, v.w);
    }
    reinterpret_cast<float4*>(pooled)[((size_t)(which * NN + n)) * 256 + d4] = m;
}

// ---------------------------------------------------------------------------
// Kernel 2: fp32 GEMM, split-K.  partial_g[ksl][m][h] = sum_{k in slice}
// A[m][k] * W1[h][koff+k].  BM=BN=128, 256 thr (16x16), micro-tile 8x8,
// K-slice 128 (4 chunks of BK=32). grid (8 n, 4 m, 8 ksl) = 256 blocks.
// LDS tiles [128][32] with float4 XOR swizzle quad^=(row>>3)&7:
// conflict-free 8-row-stride ds_read_b128 on both A and B fragments.
// 16 b128 reads per 256 FMA (1 B/FMA). Register prefetch of next chunk.
// ---------------------------------------------------------------------------
__global__ __launch_bounds__(256, 1) void gemm_kernel(const float* __restrict__ A,
                                                      const float* __restrict__ W1,
                                                      float* __restrict__ partial_g) {
    __shared__ float As[128 * 32];
    __shared__ float Bs[128 * 32];
    const int t = threadIdx.x;
    const int tn = t & 15;   // n-oct: cols tn*8 .. +7
    const int tm = t >> 4;   // m-oct: rows tm*8 .. +7
    const int n0 = blockIdx.x * 128;
    const int m0 = blockIdx.y * 128;
    const int ksl = blockIdx.z;
    const int koff = (m0 < NN) ? 0 : DD;
    const int kbA = ksl * 128;          // col offset into A (DD cols)
    const int kbB = koff + ksl * 128;   // col offset into W1 row (2*DD cols)

    // staging ids: thread stages 4 float4 per tile, rows sr+32s, quad sq
    const int sq = t & 7;
    const int sr = t >> 3;   // 0..31

    float acc[8][8];
#pragma unroll
    for (int i = 0; i < 8; ++i)
#pragma unroll
        for (int j = 0; j < 8; ++j) acc[i][j] = 0.f;

    float4* As4 = reinterpret_cast<float4*>(As);
    float4* Bs4 = reinterpret_cast<float4*>(Bs);

    // prologue: chunk 0
    float4 pa[4], pb[4];
#pragma unroll
    for (int s = 0; s < 4; ++s) {
        pa[s] = *(const float4*)&A[(size_t)(m0 + sr + 32 * s) * DD + kbA + sq * 4];
        pb[s] = *(const float4*)&W1[(size_t)(n0 + sr + 32 * s) * (2 * DD) + kbB + sq * 4];
    }
#pragma unroll
    for (int s = 0; s < 4; ++s) {
        const int r = sr + 32 * s;
        const int q = sq ^ ((r >> 3) & 7);
        As4[r * 8 + q] = pa[s];
        Bs4[r * 8 + q] = pb[s];
    }
    __syncthreads();

    for (int ch = 0; ch < 4; ++ch) {
        float4 na[4], nb[4];
        if (ch < 3) {
            const int kg = (ch + 1) * 32;
#pragma unroll
            for (int s = 0; s < 4; ++s) {
                na[s] = *(const float4*)&A[(size_t)(m0 + sr + 32 * s) * DD + kbA + kg + sq * 4];
                nb[s] = *(const float4*)&W1[(size_t)(n0 + sr + 32 * s) * (2 * DD) + kbB + kg + sq * 4];
            }
        }
#pragma unroll
        for (int kq = 0; kq < 8; ++kq) {
            float4 av[8], bv[8];
#pragma unroll
            for (int i = 0; i < 8; ++i) av[i] = As4[(tm * 8 + i) * 8 + (kq ^ (tm & 7))];
#pragma unroll
            for (int j = 0; j < 8; ++j) bv[j] = Bs4[(tn * 8 + j) * 8 + (kq ^ (tn & 7))];
#pragma unroll
            for (int i = 0; i < 8; ++i)
#pragma unroll
                for (int j = 0; j < 8; ++j) {
                    acc[i][j] += av[i].x * bv[j].x;
                    acc[i][j] += av[i].y * bv[j].y;
                    acc[i][j] += av[i].z * bv[j].z;
                    acc[i][j] += av[i].w * bv[j].w;
                }
        }
        __syncthreads();
        if (ch < 3) {
#pragma unroll
            for (int s = 0; s < 4; ++s) {
                const int r = sr + 32 * s;
                const int q = sq ^ ((r >> 3) & 7);
                As4[r * 8 + q] = na[s];
                Bs4[r * 8 + q] = nb[s];
            }
            __syncthreads();
        }
    }

    // epilogue: write 128x128 partial tile for this k-slice
    float* outp = partial_g + (size_t)ksl * (2 * NN) * HH;
#pragma unroll
    for (int i = 0; i < 8; ++i) {
        const int row = m0 + tm * 8 + i;
        float4 r0 = make_float4(acc[i][0], acc[i][1], acc[i][2], acc[i][3]);
        float4 r1 = make_float4(acc[i][4], acc[i][5], acc[i][6], acc[i][7]);
        *(float4*)&outp[(size_t)row * HH + n0 + tn * 8 + 0] = r0;
        *(float4*)&outp[(size_t)row * HH + n0 + tn * 8 + 4] = r1;
    }
}

// Kernel 2b: sum 8 k-slices + bias (subject rows only). grid 512, block 256.
__global__ __launch_bounds__(256) void gemm_reduce(const float* __restrict__ partial_g,
                                                   const float* __restrict__ b1,
                                                   float* __restrict__ sp_op) {
    const int m = blockIdx.x;
    const int d4 = threadIdx.x;
    const float4* p = reinterpret_cast<const float4*>(partial_g) + (size_t)m * 256 + d4;
    const size_t stride = (size_t)(2 * NN) * 256;  // one ksl step, f4 units
    float4 s = p[0];
#pragma unroll
    for (int ksl = 1; ksl < 8; ++ksl) {
        float4 v = p[(size_t)ksl * stride];
        s.x += v.x; s.y += v.y; s.z += v.z; s.w += v.w;
    }
    if (m < NN) {
        float4 b = reinterpret_cast<const float4*>(b1)[d4];
        s.x += b.x; s.y += b.y; s.z += b.z; s.w += b.w;
    }
    reinterpret_cast<float4*>(sp_op)[(size_t)m * 256 + d4] = s;
}

// ---------------------------------------------------------------------------
// Kernel 3: pair scores.  scores[i,j] = sum_h relu(sp[i,h]+op[j,h]) * w2[h] + b2
// grid (16,16), 256 threads, 1 pair/thread. LDS tiles with register prefetch;
// W2 read block-uniform -> scalar loads.
// ---------------------------------------------------------------------------
#define HC 128

__global__ __launch_bounds__(256) void pair_kernel(const float* __restrict__ sp_op,
                                                   const float* __restrict__ W2,
                                                   const float* __restrict__ b2,
                                                   float* __restrict__ out) {
    __shared__ float sT[16][HC + 4];
    __shared__ float oT[16][HC + 4];
    const int t = threadIdx.x;
    const int tx = t & 15, ty = t >> 4;
    const int i0 = blockIdx.y * 16, j0 = blockIdx.x * 16;
    const float* sp = sp_op;                    // rows 0..255 (b1 folded)
    const float* op = sp_op + (size_t)NN * HH;  // rows 256..511

    const int s_row = t >> 5;       // 0..7; +8 in round 1
    const int s_h = (t & 31) * 4;   // 0..124

    float4 rs[2], ro[2];
#pragma unroll
    for (int r = 0; r < 2; ++r) {
        const int row = s_row + r * 8;
        rs[r] = *(const float4*)&sp[(size_t)(i0 + row) * HH + s_h];
        ro[r] = *(const float4*)&op[(size_t)(j0 + row) * HH + s_h];
    }

    float acc = 0.f;
    for (int c = 0; c < HH / HC; ++c) {
#pragma unroll
        for (int r = 0; r < 2; ++r) {
            const int row = s_row + r * 8;
            *(float4*)&sT[row][s_h] = rs[r];
            *(float4*)&oT[row][s_h] = ro[r];
        }
        float4 ns[2], no[2];
        if (c + 1 < HH / HC) {
#pragma unroll
            for (int r = 0; r < 2; ++r) {
                const int row = s_row + r * 8;
                ns[r] = *(const float4*)&sp[(size_t)(i0 + row) * HH + (c + 1) * HC + s_h];
                no[r] = *(const float4*)&op[(size_t)(j0 + row) * HH + (c + 1) * HC + s_h];
            }
        }
        __syncthreads();
#pragma unroll
        for (int h4 = 0; h4 < HC / 4; ++h4) {
            float4 s = *(const float4*)&sT[ty][h4 * 4];
            float4 o = *(const float4*)&oT[tx][h4 * 4];
            float4 w = *(const float4*)&W2[c * HC + h4 * 4];
            acc += fmaxf(s.x + o.x, 0.f) * w.x;
            acc += fmaxf(s.y + o.y, 0.f) * w.y;
            acc += fmaxf(s.z + o.z, 0.f) * w.z;
            acc += fmaxf(s.w + o.w, 0.f) * w.w;
        }
        __syncthreads();
        if (c + 1 < HH / HC) {
#pragma unroll
            for (int r = 0; r < 2; ++r) { rs[r] = ns[r]; ro[r] = no[r]; }
        }
    }
    const int i = i0 + ty, j = j0 + tx;
    const float score = acc + b2[0];
    out[i * NN + j] = (i == j) ? 0.f : score;
}

// ---------------------------------------------------------------------------
extern "C" void kernel_launch(void* const* d_in, const int* in_sizes, int n_in,
                              void* d_out, int out_size, void* d_ws, size_t ws_size,
                              hipStream_t stream) {
    const float* subs = (const float*)d_in[0];
    const float* objs = (const float*)d_in[1];
    const float* W1   = (const float*)d_in[2];
    const float* b1   = (const float*)d_in[3];
    const float* W2   = (const float*)d_in[4];
    const float* b2   = (const float*)d_in[5];
    float* out = (float*)d_out;

    float* partial_p = (float*)d_ws;                            // [16][256][1024] = 16 MB
    float* pooled    = partial_p + (size_t)16 * NN * DD;        // [512][1024] = 2 MB
    float* partial_g = pooled + (size_t)2 * NN * DD;            // [8][512][1024] = 16 MB
    float* sp_op     = partial_g + (size_t)8 * 2 * NN * HH;     // [512][1024] = 2 MB

    pool_partial<<<dim3(2048, 2), 256, 0, stream>>>(subs, objs, partial_p);
    pool_reduce<<<dim3(NN, 2), 256, 0, stream>>>(partial_p, pooled);
    gemm_kernel<<<dim3(8, 4, 8), 256, 0, stream>>>(pooled, W1, partial_g);
    gemm_reduce<<<dim3(2 * NN), 256, 0, stream>>>(partial_g, b1, sp_op);
    pair_kernel<<<dim3(NN / 16, NN / 16), 256, 0, stream>>>(sp_op, W2, b2, out);
}

// Round 4
// 145.198 us; speedup vs baseline: 1.6195x; 1.6195x over previous
//
#include <hip/hip_runtime.h>
#include <math.h>

#define NN 256
#define TT 256
#define DD 1024
#define HH 1024

typedef float f32x4 __attribute__((ext_vector_type(4)));
typedef short bf16x8 __attribute__((ext_vector_type(8)));

__device__ inline unsigned short f2bf_rne(float x) {
    unsigned u = __float_as_uint(x);
    unsigned r = (u + 0x7fffu + ((u >> 16) & 1u)) >> 16;
    return (unsigned short)r;
}
__device__ inline float bf2f(unsigned short h) {
    return __uint_as_float(((unsigned)h) << 16);
}

// ---------------------------------------------------------------------------
// Kernel 1: max-pool over token dim. grid (256, 2), block 256.
// R1 geometry (1 MB contiguous per block — best measured) + nontemporal
// loads (bypass L3: the mixed L3-hit/HBM-miss path measured 3.2 TB/s) +
// 8-deep load pipeline. Thread d4 owns a float4 column, walks 256 t-rows.
// ---------------------------------------------------------------------------
__global__ __launch_bounds__(256) void pool_kernel(const float* __restrict__ subs,
                                                   const float* __restrict__ objs,
                                                   float* __restrict__ pooled) {
    const int n = blockIdx.x;
    const int which = blockIdx.y;
    const f32x4* src = reinterpret_cast<const f32x4*>(which == 0 ? subs : objs);
    const int d4 = threadIdx.x;
    const f32x4* base = src + (((size_t)n) << 16) + d4;

    f32x4 a[8];
#pragma unroll
    for (int s = 0; s < 8; ++s) a[s] = (f32x4){-INFINITY, -INFINITY, -INFINITY, -INFINITY};

    for (int k = 0; k < 256; k += 8) {
        f32x4 v[8];
#pragma unroll
        for (int s = 0; s < 8; ++s)
            v[s] = __builtin_nontemporal_load(base + (size_t)(k + s) * 256);
#pragma unroll
        for (int s = 0; s < 8; ++s) {
#pragma unroll
            for (int e = 0; e < 4; ++e) a[s][e] = fmaxf(a[s][e], v[s][e]);
        }
    }
#pragma unroll
    for (int s = 0; s < 4; ++s)
#pragma unroll
        for (int e = 0; e < 4; ++e) a[s][e] = fmaxf(a[s][e], a[s + 4][e]);
    f32x4 m;
#pragma unroll
    for (int e = 0; e < 4; ++e)
        m[e] = fmaxf(fmaxf(a[0][e], a[1][e]), fmaxf(a[2][e], a[3][e]));

    reinterpret_cast<f32x4*>(pooled)[((size_t)(which * NN + n)) * 256 + d4] = m;
}

// ---------------------------------------------------------------------------
// Kernel 2: GEMM via bf16 hi/lo split MFMA (3x mfma_f32_16x16x32_bf16:
// hi*hi + hi*lo + lo*hi recovers ~fp32 precision, err ~2^-16 rel).
// out[m][h] = sum_d A[m][d] * W1[h][koff+d] (+b1 if m<256).
// Tiles 64m x 32n, grid (32, 8) = 256 blocks, 4 waves (2m x 2n of 32x16).
// LDS: bf16 tiles row-padded to 40 elems (80 B -> row stride 20 banks,
// conflict-free b128 fragment reads). Fragment layout per guide:
// A/B: row(col)=lane&15, k=(lane>>4)*8+j ; C/D: col=lane&15, row=(lane>>4)*4+reg.
// ---------------------------------------------------------------------------
__global__ __launch_bounds__(256, 1) void gemm_kernel(const float* __restrict__ A,
                                                      const float* __restrict__ W1,
                                                      const float* __restrict__ b1,
                                                      float* __restrict__ out) {
    __shared__ unsigned short Ah[64 * 40];
    __shared__ unsigned short Al[64 * 40];
    __shared__ unsigned short Bh[32 * 40];
    __shared__ unsigned short Bl[32 * 40];

    const int t = threadIdx.x;
    const int lane = t & 63;
    const int w = t >> 6;
    const int wm = w >> 1, wn = w & 1;
    const int n0 = blockIdx.x * 32;
    const int m0 = blockIdx.y * 64;
    const bool is_sub = (m0 < NN);
    const int koff = is_sub ? 0 : DD;

    // staging geometry
    const int ar = t >> 2;              // 0..63
    const int akq = (t & 3) * 8;        // 0,8,16,24
    const int br = (t & 127) >> 2;      // 0..31 (threads <128 stage B)
    const int bkq = akq;

    f32x4 acc0 = {0.f, 0.f, 0.f, 0.f};
    f32x4 acc1 = {0.f, 0.f, 0.f, 0.f};

    // fragment LDS indices (ushort units)
    const int iA0 = (wm * 32 + (lane & 15)) * 40 + (lane >> 4) * 8;
    const int iA1 = (wm * 32 + 16 + (lane & 15)) * 40 + (lane >> 4) * 8;
    const int iB  = (wn * 16 + (lane & 15)) * 40 + (lane >> 4) * 8;

    for (int ch = 0; ch < 32; ++ch) {
        const int kb = ch * 32;
        // global loads (issued before sync -> latency hidden under prev compute)
        const float* ap = A + (size_t)(m0 + ar) * DD + kb + akq;
        f32x4 av0 = *(const f32x4*)ap;
        f32x4 av1 = *(const f32x4*)(ap + 4);
        f32x4 bv0, bv1;
        if (t < 128) {
            const float* bp = W1 + (size_t)(n0 + br) * (2 * DD) + koff + kb + bkq;
            bv0 = *(const f32x4*)bp;
            bv1 = *(const f32x4*)(bp + 4);
        }
        __syncthreads();  // previous chunk's compute done

        // convert + pack + LDS write
        {
            float xs[8];
#pragma unroll
            for (int e = 0; e < 4; ++e) { xs[e] = av0[e]; xs[4 + e] = av1[e]; }
            unsigned hw[4], lw[4];
#pragma unroll
            for (int p = 0; p < 4; ++p) {
                unsigned short h0 = f2bf_rne(xs[2 * p]);
                unsigned short h1 = f2bf_rne(xs[2 * p + 1]);
                unsigned short l0 = f2bf_rne(xs[2 * p] - bf2f(h0));
                unsigned short l1 = f2bf_rne(xs[2 * p + 1] - bf2f(h1));
                hw[p] = (unsigned)h0 | ((unsigned)h1 << 16);
                lw[p] = (unsigned)l0 | ((unsigned)l1 << 16);
            }
            *(uint4*)&Ah[ar * 40 + akq] = make_uint4(hw[0], hw[1], hw[2], hw[3]);
            *(uint4*)&Al[ar * 40 + akq] = make_uint4(lw[0], lw[1], lw[2], lw[3]);
        }
        if (t < 128) {
            float xs[8];
#pragma unroll
            for (int e = 0; e < 4; ++e) { xs[e] = bv0[e]; xs[4 + e] = bv1[e]; }
            unsigned hw[4], lw[4];
#pragma unroll
            for (int p = 0; p < 4; ++p) {
                unsigned short h0 = f2bf_rne(xs[2 * p]);
                unsigned short h1 = f2bf_rne(xs[2 * p + 1]);
                unsigned short l0 = f2bf_rne(xs[2 * p] - bf2f(h0));
                unsigned short l1 = f2bf_rne(xs[2 * p + 1] - bf2f(h1));
                hw[p] = (unsigned)h0 | ((unsigned)h1 << 16);
                lw[p] = (unsigned)l0 | ((unsigned)l1 << 16);
            }
            *(uint4*)&Bh[br * 40 + bkq] = make_uint4(hw[0], hw[1], hw[2], hw[3]);
            *(uint4*)&Bl[br * 40 + bkq] = make_uint4(lw[0], lw[1], lw[2], lw[3]);
        }
        __syncthreads();  // staging visible

        bf16x8 a0h = *(const bf16x8*)&Ah[iA0];
        bf16x8 a0l = *(const bf16x8*)&Al[iA0];
        bf16x8 a1h = *(const bf16x8*)&Ah[iA1];
        bf16x8 a1l = *(const bf16x8*)&Al[iA1];
        bf16x8 bh  = *(const bf16x8*)&Bh[iB];
        bf16x8 bl  = *(const bf16x8*)&Bl[iB];

        acc0 = __builtin_amdgcn_mfma_f32_16x16x32_bf16(a0h, bh, acc0, 0, 0, 0);
        acc0 = __builtin_amdgcn_mfma_f32_16x16x32_bf16(a0h, bl, acc0, 0, 0, 0);
        acc0 = __builtin_amdgcn_mfma_f32_16x16x32_bf16(a0l, bh, acc0, 0, 0, 0);
        acc1 = __builtin_amdgcn_mfma_f32_16x16x32_bf16(a1h, bh, acc1, 0, 0, 0);
        acc1 = __builtin_amdgcn_mfma_f32_16x16x32_bf16(a1h, bl, acc1, 0, 0, 0);
        acc1 = __builtin_amdgcn_mfma_f32_16x16x32_bf16(a1l, bh, acc1, 0, 0, 0);
    }

    // epilogue: C/D layout col=lane&15, row=(lane>>4)*4+reg; fold b1 for subjects
    const int col = n0 + wn * 16 + (lane & 15);
    const float bias = is_sub ? b1[col] : 0.f;
    const int rb = m0 + wm * 32 + (lane >> 4) * 4;
#pragma unroll
    for (int r = 0; r < 4; ++r) {
        out[(size_t)(rb + r) * HH + col] = acc0[r] + bias;
        out[(size_t)(rb + 16 + r) * HH + col] = acc1[r] + bias;
    }
}

// ---------------------------------------------------------------------------
// Kernel 3: pair scores.  scores[i,j] = sum_h relu(sp[i,h]+op[j,h]) * w2[h] + b2
// grid (16,16), 256 threads, 1 pair/thread. LDS tiles + register prefetch;
// W2 read block-uniform -> scalar loads.
// ---------------------------------------------------------------------------
#define HC 128

__global__ __launch_bounds__(256) void pair_kernel(const float* __restrict__ sp_op,
                                                   const float* __restrict__ W2,
                                                   const float* __restrict__ b2,
                                                   float* __restrict__ out) {
    __shared__ float sT[16][HC + 4];
    __shared__ float oT[16][HC + 4];
    const int t = threadIdx.x;
    const int tx = t & 15, ty = t >> 4;
    const int i0 = blockIdx.y * 16, j0 = blockIdx.x * 16;
    const float* sp = sp_op;                    // rows 0..255 (b1 folded)
    const float* op = sp_op + (size_t)NN * HH;  // rows 256..511

    const int s_row = t >> 5;       // 0..7; +8 in round 1
    const int s_h = (t & 31) * 4;   // 0..124

    float4 rs[2], ro[2];
#pragma unroll
    for (int r = 0; r < 2; ++r) {
        const int row = s_row + r * 8;
        rs[r] = *(const float4*)&sp[(size_t)(i0 + row) * HH + s_h];
        ro[r] = *(const float4*)&op[(size_t)(j0 + row) * HH + s_h];
    }

    float acc = 0.f;
    for (int c = 0; c < HH / HC; ++c) {
#pragma unroll
        for (int r = 0; r < 2; ++r) {
            const int row = s_row + r * 8;
            *(float4*)&sT[row][s_h] = rs[r];
            *(float4*)&oT[row][s_h] = ro[r];
        }
        float4 ns[2], no[2];
        if (c + 1 < HH / HC) {
#pragma unroll
            for (int r = 0; r < 2; ++r) {
                const int row = s_row + r * 8;
                ns[r] = *(const float4*)&sp[(size_t)(i0 + row) * HH + (c + 1) * HC + s_h];
                no[r] = *(const float4*)&op[(size_t)(j0 + row) * HH + (c + 1) * HC + s_h];
            }
        }
        __syncthreads();
#pragma unroll
        for (int h4 = 0; h4 < HC / 4; ++h4) {
            float4 s = *(const float4*)&sT[ty][h4 * 4];
            float4 o = *(const float4*)&oT[tx][h4 * 4];
            float4 w = *(const float4*)&W2[c * HC + h4 * 4];
            acc += fmaxf(s.x + o.x, 0.f) * w.x;
            acc += fmaxf(s.y + o.y, 0.f) * w.y;
            acc += fmaxf(s.z + o.z, 0.f) * w.z;
            acc += fmaxf(s.w + o.w, 0.f) * w.w;
        }
        __syncthreads();
        if (c + 1 < HH / HC) {
#pragma unroll
            for (int r = 0; r < 2; ++r) { rs[r] = ns[r]; ro[r] = no[r]; }
        }
    }
    const int i = i0 + ty, j = j0 + tx;
    const float score = acc + b2[0];
    out[i * NN + j] = (i == j) ? 0.f : score;
}

// ---------------------------------------------------------------------------
extern "C" void kernel_launch(void* const* d_in, const int* in_sizes, int n_in,
                              void* d_out, int out_size, void* d_ws, size_t ws_size,
                              hipStream_t stream) {
    const float* subs = (const float*)d_in[0];
    const float* objs = (const float*)d_in[1];
    const float* W1   = (const float*)d_in[2];
    const float* b1   = (const float*)d_in[3];
    const float* W2   = (const float*)d_in[4];
    const float* b2   = (const float*)d_in[5];
    float* out = (float*)d_out;

    float* pooled = (float*)d_ws;                    // [512][1024] = 2 MB
    float* sp_op  = pooled + (size_t)2 * NN * DD;    // [512][1024] = 2 MB

    pool_kernel<<<dim3(NN, 2), 256, 0, stream>>>(subs, objs, pooled);
    gemm_kernel<<<dim3(HH / 32, (2 * NN) / 64), 256, 0, stream>>>(pooled, W1, b1, sp_op);
    pair_kernel<<<dim3(NN / 16, NN / 16), 256, 0, stream>>>(sp_op, W2, b2, out);
}